// Round 4
// baseline (374.703 us; speedup 1.0000x reference)
//
#include <hip/hip_runtime.h>

typedef _Float16 f16;
typedef __attribute__((ext_vector_type(8))) _Float16 f16x8;
typedef __attribute__((ext_vector_type(4))) _Float16 f16x4;
typedef __attribute__((ext_vector_type(4))) float    f32x4;

#define B_ROWS 16384
#define MPAD   17408   // 16384 + 8 clusters * 128-row tile padding
#define MTILES 136
#define NBLK   64      // B_ROWS / 256

typedef __attribute__((address_space(1))) void as1_void;
typedef __attribute__((address_space(3))) void as3_void;

__device__ __forceinline__ void gl_lds16(const void* g, void* l) {
    __builtin_amdgcn_global_load_lds((const as1_void*)g, (as3_void*)l, 16, 0, 0);
}

// ---------------- prep: rowmap init + per-block histogram + bias concat + zerobuf ----------------

__global__ __launch_bounds__(256) void k_prep(const int* __restrict__ lbl, int* __restrict__ blockhist,
                                              int* __restrict__ rowmap,
                                              const float* __restrict__ mb_, const float* __restrict__ lb_,
                                              float* __restrict__ bz, f16* __restrict__ zerob) {
    int b = blockIdx.x, t = threadIdx.x;
    int i = b * 256 + t;               // grid = 68 blocks -> MPAD exactly
    rowmap[i] = -1;
    if (b < NBLK) {
        __shared__ int h[8];
        if (t < 8) h[t] = 0;
        __syncthreads();
        atomicAdd(&h[lbl[i]], 1);      // LDS atomic
        __syncthreads();
        if (t < 8) blockhist[b * 8 + t] = h[t];
    } else if (b == NBLK) {
        if (t < 64) zerob[t] = (f16)0.f;       // 128 B of zeros
        if (t < 64) bz[t] = mb_[t];
        else if (t < 128) bz[t] = lb_[t - 64];
    }
}

// single block: cluster totals -> padded offsets, tile->cluster map, per-block bases
__global__ void k_offsets(const int* __restrict__ blockhist, int* offs, int* tilec, int* blockbase) {
    __shared__ int tot[8];
    __shared__ int so[9];
    int t = threadIdx.x;
    if (t < 8) {
        int s = 0;
        for (int b = 0; b < NBLK; ++b) s += blockhist[b * 8 + t];
        tot[t] = s;
    }
    __syncthreads();
    if (t == 0) {
        int o = 0;
        for (int c = 0; c < 8; ++c) { so[c] = o; o += (tot[c] + 127) & ~127; }
        so[8] = o;
        for (int c = 0; c < 9; ++c) offs[c] = so[c];
    }
    __syncthreads();
    if (t < 8) {
        int run = so[t];
        for (int b = 0; b < NBLK; ++b) {
            blockbase[b * 8 + t] = run;
            run += blockhist[b * 8 + t];
        }
    }
    if (t < MTILES) {
        int row = t * 128, c = 7;
        for (int cc = 0; cc < 8; ++cc)
            if (row >= so[cc] && row < so[cc + 1]) c = cc;
        tilec[t] = c;
    }
}

// scatter: LDS cursors seeded from per-block base — zero contended global atomics
__global__ __launch_bounds__(256) void k_scatter(const int* __restrict__ lbl,
                                                 const int* __restrict__ blockbase,
                                                 int* __restrict__ rowmap) {
    __shared__ int cur[8];
    if (threadIdx.x < 8) cur[threadIdx.x] = blockbase[blockIdx.x * 8 + threadIdx.x];
    __syncthreads();
    int i = blockIdx.x * 256 + threadIdx.x;
    int c = lbl[i];
    int pos = atomicAdd(&cur[c], 1);   // LDS atomic
    rowmap[pos] = i;
}

// ---------------- merged convert + 9 weight transposes (one dispatch) ----------------
// seg 0: x fp32 -> xh f16 (32B-load/16B-store per lane).
// segs 1..9: [K,N] fp32 -> [N,K] f16, 64x64 tiles, float4 loads + in-reg 4x4 transpose +
//            LDS + f16x8 stores (16B global writes).

struct Seg { const float* s; f16* d; int K, N, b0, nx, ny; long sCS, dCS; };
struct SegTab { Seg g[10]; };

__global__ __launch_bounds__(256) void k_trans(SegTab tab, const float* __restrict__ x, f16* __restrict__ xh) {
    int bid = blockIdx.x;
    int t = threadIdx.x;
    if (bid < tab.g[1].b0) {           // cvt segment: 4096 blocks, 8 floats/thread
        long i = (long)bid * 256 + t;
        const float4* xs = (const float4*)x;
        float4 v0 = xs[i * 2], v1 = xs[i * 2 + 1];
        f16x8 o = {(f16)v0.x, (f16)v0.y, (f16)v0.z, (f16)v0.w,
                   (f16)v1.x, (f16)v1.y, (f16)v1.z, (f16)v1.w};
        ((f16x8*)xh)[i] = o;
        return;
    }
    int s = 9;
    while (bid < tab.g[s].b0) --s;     // block-uniform linear search
    Seg sg = tab.g[s];
    int lb = bid - sg.b0;
    int nxy = sg.nx * sg.ny;
    int z = lb / nxy; int r = lb - z * nxy;
    int by = r / sg.nx; int bx = r - by * sg.nx;   // by: k-tile, bx: n-tile
    const float* src = sg.s + (size_t)z * sg.sCS;
    f16* dst = sg.d + (size_t)z * sg.dCS;
    int k0 = by * 64, n0 = bx * 64;

    __shared__ f16 tr[64][88];         // row = n (dst row), 176B stride: 8-group bank spread
    int a = t & 15, b = t >> 4;        // a: n-micro (4 cols), b: k-micro (4 rows)
    float4 v[4];
    #pragma unroll
    for (int i = 0; i < 4; ++i)
        v[i] = *(const float4*)&src[(size_t)(k0 + b * 4 + i) * sg.N + n0 + a * 4];
    #pragma unroll
    for (int j = 0; j < 4; ++j) {
        f16x4 w = {(f16)((const float*)&v[0])[j], (f16)((const float*)&v[1])[j],
                   (f16)((const float*)&v[2])[j], (f16)((const float*)&v[3])[j]};
        *(f16x4*)&tr[a * 4 + j][b * 4] = w;
    }
    __syncthreads();
    int n = t >> 2, s4 = t & 3;
    f16x8 o0 = *(const f16x8*)&tr[n][s4 * 16];
    f16x8 o1 = *(const f16x8*)&tr[n][s4 * 16 + 8];
    *(f16x8*)&dst[(size_t)(n0 + n) * sg.K + k0 + s4 * 16] = o0;
    *(f16x8*)&dst[(size_t)(n0 + n) * sg.K + k0 + s4 * 16 + 8] = o1;
}

__global__ __launch_bounds__(256) void k_reparam(const f16* __restrict__ muv, const float* __restrict__ eps,
                                                 const int* __restrict__ rowmap, f16* __restrict__ z) {
    int i = blockIdx.x * 256 + threadIdx.x;   // MPAD*64 exactly
    int p = i >> 6, j = i & 63;
    int g = rowmap[p];
    float e  = (g >= 0) ? eps[(size_t)g * 64 + j] : 0.f;
    float mu = (float)muv[(size_t)p * 128 + j];
    float lv = (float)muv[(size_t)p * 128 + 64 + j];
    z[i] = (f16)(mu + expf(0.5f * lv) * e);
}

// ---------------- MFMA GEMM: 128x128 tile, BK=64, DOUBLE-BUFFERED single-barrier K-loop -------
// A [*, K] f16 (GATHER: rows via rowmap), Wt [C?, N, K] f16, bias [C?, N] fp32.
// Out f16 [MPAD, N]  (SCATTER: fp32 d_out rows via rowmap)
// XOR-swizzled LDS (2-way = free), XCD-aware 1-D grid.
// Pipeline: iter k: barrier (drains loads of buf[cur], issued one full compute phase ago)
//           -> issue loads(k+1) into buf[nxt] -> ds_read+MFMA on buf[cur]. One barrier/iter;
//           the forced vmcnt(0)-at-barrier lands after ~32 MFMA x 8 waves of cover.

template<int GATHER, int PERW, int RELU, int SCATTER>
__global__ __launch_bounds__(256, 2) void gemm_k(
    const f16* __restrict__ A, const f16* __restrict__ Wt,
    const float* __restrict__ bias, f16* __restrict__ Out, float* __restrict__ OutF,
    const int* __restrict__ rowmap, const int* __restrict__ tilec,
    const f16* __restrict__ zerobuf, int K, int N)
{
    __shared__ __align__(16) f16 lA[2][128 * 64];   // 16 KB x2
    __shared__ __align__(16) f16 lB[2][128 * 64];   // 16 KB x2  (64 KB total -> 2 blocks/CU)
    const int tid  = threadIdx.x;
    const int wave = tid >> 6;
    const int lane = tid & 63;

    // XCD-aware swizzle: blocks sharing an A row-tile (same tm) land on the same XCD (id mod 8)
    const int id  = blockIdx.x;
    const int xcd = id & 7;
    const int jj  = id >> 3;
    const int tm  = (jj % 17) * 8 + xcd;   // 0..135
    const int tn  = jj / 17;
    const int r0 = tm * 128, n0 = tn * 128;

    const f16* wb = Wt;
    const float* bb = bias;
    if (PERW) {
        int c = tilec[tm];
        wb += (size_t)c * K * N;
        bb += (size_t)c * N;
    }

    // staging: thread t loads granule (sg ^ (srow&7)) of row (pass*32 + srow) each k-chunk
    const int srow = tid >> 3;             // 0..31
    const int sg   = tid & 7;              // 0..7
    const int xk16 = (sg ^ (srow & 7)) * 16;
    const size_t rowB = (size_t)K * 2;     // bytes per row
    const size_t passB = 32 * rowB;        // bytes per 32-row pass group

    const char* pa[4]; size_t stepA[4];
    #pragma unroll
    for (int p = 0; p < 4; ++p) {
        int gr = r0 + p * 32 + srow;
        if (GATHER) {
            int g = rowmap[gr];
            if (g >= 0) { pa[p] = (const char*)(A + (size_t)g * K) + xk16; stepA[p] = 128; }
            else        { pa[p] = (const char*)zerobuf;                    stepA[p] = 0;   }
        } else {
            pa[p] = (const char*)(A + (size_t)gr * K) + xk16; stepA[p] = 128;
        }
    }
    const char* pb = (const char*)(wb + (size_t)(n0 + srow) * K) + xk16;

    const int mb = (wave >> 1) * 64;
    const int nb = (wave & 1) * 64;
    const int quad = lane >> 4;
    const int r16  = lane & 15;
    const int key  = r16 & 7;

    f32x4 acc[4][4];
    #pragma unroll
    for (int i = 0; i < 4; ++i)
        #pragma unroll
        for (int j = 0; j < 4; ++j)
            acc[i][j] = (f32x4){0.f, 0.f, 0.f, 0.f};

    const int nk = K >> 6;

    // prologue: issue tile 0 into buf 0
    #pragma unroll
    for (int p = 0; p < 4; ++p)
        gl_lds16(pa[p], (char*)lA[0] + p * 4096 + wave * 1024);
    #pragma unroll
    for (int p = 0; p < 4; ++p)
        gl_lds16(pb + p * passB, (char*)lB[0] + p * 4096 + wave * 1024);
    #pragma unroll
    for (int p = 0; p < 4; ++p) pa[p] += stepA[p];
    pb += 128;

    for (int kb = 0; kb < nk; ++kb) {
        const int cur = kb & 1, nxt = cur ^ 1;
        __syncthreads();   // drains buf[cur] loads (issued one compute-phase ago)
        if (kb + 1 < nk) { // prefetch next tile into the other buffer
            #pragma unroll
            for (int p = 0; p < 4; ++p)
                gl_lds16(pa[p], (char*)lA[nxt] + p * 4096 + wave * 1024);
            #pragma unroll
            for (int p = 0; p < 4; ++p)
                gl_lds16(pb + p * passB, (char*)lB[nxt] + p * 4096 + wave * 1024);
            #pragma unroll
            for (int p = 0; p < 4; ++p) pa[p] += stepA[p];
            pb += 128;
        }
        #pragma unroll
        for (int kk = 0; kk < 2; ++kk) {
            const int off = ((kk * 4 + quad) ^ key) * 16;
            f16x8 af[4], bf[4];
            #pragma unroll
            for (int i = 0; i < 4; ++i)
                af[i] = *(const f16x8*)((const char*)lA[cur] + (mb + i * 16 + r16) * 128 + off);
            #pragma unroll
            for (int j = 0; j < 4; ++j)
                bf[j] = *(const f16x8*)((const char*)lB[cur] + (nb + j * 16 + r16) * 128 + off);
            #pragma unroll
            for (int i = 0; i < 4; ++i)
                #pragma unroll
                for (int j = 0; j < 4; ++j)
                    acc[i][j] = __builtin_amdgcn_mfma_f32_16x16x32_f16(af[i], bf[j], acc[i][j], 0, 0, 0);
        }
    }

    float bv[4];
    #pragma unroll
    for (int j = 0; j < 4; ++j) bv[j] = bb[n0 + nb + j * 16 + r16];

    #pragma unroll
    for (int i = 0; i < 4; ++i) {
        #pragma unroll
        for (int r = 0; r < 4; ++r) {
            int orow = r0 + mb + i * 16 + quad * 4 + r;
            int g = 0;
            if (SCATTER) g = rowmap[orow];
            #pragma unroll
            for (int j = 0; j < 4; ++j) {
                int ocol = n0 + nb + j * 16 + r16;
                float v = acc[i][j][r] + bv[j];
                if (RELU) v = fmaxf(v, 0.f);
                if (SCATTER) {
                    if (g >= 0) OutF[(size_t)g * N + ocol] = v;
                } else {
                    Out[(size_t)orow * N + ocol] = (f16)v;
                }
            }
        }
    }
}

// ---------------- launch ----------------

extern "C" void kernel_launch(void* const* d_in, const int* in_sizes, int n_in,
                              void* d_out, int out_size, void* d_ws, size_t ws_size,
                              hipStream_t stream) {
    const float* x      = (const float*)d_in[0];
    const int*   lbl    = (const int*)  d_in[1];
    const float* eps    = (const float*)d_in[2];
    const float* enc_W0 = (const float*)d_in[3];
    const float* enc_b0 = (const float*)d_in[4];
    const float* enc_Wu = (const float*)d_in[5];
    const float* enc_bu = (const float*)d_in[6];
    const float* enc_W2 = (const float*)d_in[7];
    const float* enc_b2 = (const float*)d_in[8];
    const float* mu_W   = (const float*)d_in[9];
    const float* mu_b   = (const float*)d_in[10];
    const float* lv_W   = (const float*)d_in[11];
    const float* lv_b   = (const float*)d_in[12];
    const float* dWu0   = (const float*)d_in[13];
    const float* dbu0   = (const float*)d_in[14];
    const float* dW1    = (const float*)d_in[15];
    const float* db1    = (const float*)d_in[16];
    const float* dWu2   = (const float*)d_in[17];
    const float* dbu2   = (const float*)d_in[18];
    const float* finW   = (const float*)d_in[19];
    const float* finb   = (const float*)d_in[20];
    float* out = (float*)d_out;
    (void)in_sizes; (void)n_in; (void)out_size; (void)ws_size;

    char* base = (char*)d_ws;
    size_t off = 0;
    auto alloc = [&](size_t bytes) { char* r = base + off; off = (off + bytes + 255) & ~(size_t)255; return r; };
    f16* xh     = (f16*)alloc((size_t)B_ROWS * 512 * 2);
    f16* buf1   = (f16*)alloc((size_t)MPAD * 1024 * 2);  // h1 / h6
    f16* buf2   = (f16*)alloc((size_t)MPAD * 512 * 2);   // h2 / h5
    f16* buf3   = (f16*)alloc((size_t)MPAD * 256 * 2);   // h3 / h4
    f16* muv    = (f16*)alloc((size_t)MPAD * 128 * 2);   // [mu|logvar]
    f16* zb     = (f16*)alloc((size_t)MPAD * 64 * 2);
    f16* w0t    = (f16*)alloc(1024ul * 512 * 2);
    f16* wut    = (f16*)alloc(8ul * 512 * 1024 * 2);
    f16* w2t    = (f16*)alloc(256ul * 512 * 2);
    f16* wzt    = (f16*)alloc(128ul * 256 * 2);
    f16* wd0t   = (f16*)alloc(8ul * 256 * 64 * 2);
    f16* wd1t   = (f16*)alloc(512ul * 256 * 2);
    f16* wd2t   = (f16*)alloc(8ul * 1024 * 512 * 2);
    f16* wft    = (f16*)alloc(8ul * 512 * 1024 * 2);
    float* bz   = (float*)alloc(128 * 4);
    int* rowmap = (int*)alloc(MPAD * 4);
    int* blockhist = (int*)alloc(NBLK * 8 * 4);
    int* blockbase = (int*)alloc(NBLK * 8 * 4);
    int* offs   = (int*)alloc(64);
    int* tilec  = (int*)alloc(MTILES * 4);
    f16* zerob  = (f16*)alloc(256);

    // cluster sort + bias concat
    k_prep<<<MPAD / 256, 256, 0, stream>>>(lbl, blockhist, rowmap, mu_b, lv_b, bz, zerob);
    k_offsets<<<1, 256, 0, stream>>>(blockhist, offs, tilec, blockbase);
    k_scatter<<<NBLK, 256, 0, stream>>>(lbl, blockbase, rowmap);

    // merged convert + transposes: seg0 cvt (4096 blocks), segs 1..9 transposes (64x64 tiles)
    SegTab tab;
    int b0 = B_ROWS * 512 / 8 / 256;   // 4096
    auto seg = [&](int i, const float* s, f16* d, int K, int N, int nz, long sCS, long dCS) {
        int nx = N / 64, ny = K / 64;
        tab.g[i] = Seg{s, d, K, N, b0, nx, ny, sCS, dCS};
        b0 += nx * ny * nz;
    };
    tab.g[0] = Seg{nullptr, nullptr, 0, 0, 0, 0, 0, 0, 0};
    seg(1, enc_W0, w0t, 512, 1024, 1, 0, 0);
    seg(2, enc_Wu, wut, 1024, 512, 8, 1024l * 512, 512l * 1024);
    seg(3, enc_W2, w2t, 512, 256, 1, 0, 0);
    seg(4, mu_W, wzt, 256, 64, 1, 0, 0);
    seg(5, lv_W, wzt + 64 * 256, 256, 64, 1, 0, 0);
    seg(6, dWu0, wd0t, 64, 256, 8, 64l * 256, 256l * 64);
    seg(7, dW1, wd1t, 256, 512, 1, 0, 0);
    seg(8, dWu2, wd2t, 512, 1024, 8, 512l * 1024, 1024l * 512);
    seg(9, finW, wft, 1024, 512, 8, 1024l * 512, 512l * 1024);
    k_trans<<<b0, 256, 0, stream>>>(tab, x, xh);

    // encoder
    gemm_k<1,0,1,0><<<MTILES * 8, 256, 0, stream>>>(xh,   w0t,  enc_b0, buf1, nullptr, rowmap, tilec, zerob, 512, 1024);
    gemm_k<0,1,1,0><<<MTILES * 4, 256, 0, stream>>>(buf1, wut,  enc_bu, buf2, nullptr, rowmap, tilec, zerob, 1024, 512);
    gemm_k<0,0,1,0><<<MTILES * 2, 256, 0, stream>>>(buf2, w2t,  enc_b2, buf3, nullptr, rowmap, tilec, zerob, 512, 256);
    // latent heads (mu|logvar fused, no relu) + reparameterize
    gemm_k<0,0,0,0><<<MTILES * 1, 256, 0, stream>>>(buf3, wzt,  bz,     muv,  nullptr, rowmap, tilec, zerob, 256, 128);
    k_reparam<<<MPAD * 64 / 256, 256, 0, stream>>>(muv, eps, rowmap, zb);
    // decoder
    gemm_k<0,1,1,0><<<MTILES * 2, 256, 0, stream>>>(zb,   wd0t, dbu0,   buf3, nullptr, rowmap, tilec, zerob, 64, 256);
    gemm_k<0,0,1,0><<<MTILES * 4, 256, 0, stream>>>(buf3, wd1t, db1,    buf2, nullptr, rowmap, tilec, zerob, 256, 512);
    gemm_k<0,1,1,0><<<MTILES * 8, 256, 0, stream>>>(buf2, wd2t, dbu2,   buf1, nullptr, rowmap, tilec, zerob, 512, 1024);
    // final per-cluster layer, fp32 scatter to d_out
    gemm_k<0,1,0,1><<<MTILES * 4, 256, 0, stream>>>(buf1, wft,  finb,   nullptr, out,  rowmap, tilec, zerob, 1024, 512);
}